// Round 12
// baseline (493.013 us; speedup 1.0000x reference)
//
#include <hip/hip_runtime.h>

// PASSED with absmax = 0.0 (bitwise match vs np reference).
// FROZEN: all fp arithmetic (per-element gemm fmaf chain, k ascending;
// attn per-edge ops and per-(dst,channel) ascending-edge-id summation).
// Integer/layout/scheduling changes only.
// R11: attn FETCH=304MB = 8 XCDs x ~38MB -> each XCD's 4MB L2 thrashes over
// the whole 41MB KV table. Fix: 8 channel-slices (5.12MB each), slice-major
// KV layout, grid gid = dblock*8 + slice so round-robin dispatch pins slice s
// to XCD s. Wave = 8 dsts x 16 channels. Degree-sorted dst permutation
// (counting sort) equalizes deg within a wave. All bitwise-preserving.

#define FMA4(acc, s, b) do { \
    (acc).x = fmaf((s), (b).x, (acc).x); \
    (acc).y = fmaf((s), (b).y, (acc).y); \
    (acc).z = fmaf((s), (b).z, (acc).z); \
    (acc).w = fmaf((s), (b).w, (acc).w); } while (0)

// ---------------------------------------------------------------------------
// fp32 GEMM, 128x128 tile per block, 8x8 per thread, K in 4 chunks of 32.
// which=0 -> Qf[n][128]; which=1/2 -> K/V halves of sliced KVs.
// Per-output-element arithmetic: single accumulator, fmaf, k ascending. FROZEN.
// KVs layout: float4 slot index ((s*N + n)*8 + j), slot = [k2p,k2p+1,v2p,v2p+1]
// for channel pair p = s*8 + j.
// ---------------------------------------------------------------------------
__global__ __launch_bounds__(256) void gemm_qkv(
    const float* __restrict__ h,
    const float* __restrict__ WQ,
    const float* __restrict__ WK,
    const float* __restrict__ WV,
    float* __restrict__ Qf,
    float* __restrict__ KVs,
    int N)
{
    __shared__ float4 Wl[32 * 32];   // [k][c4]            16 KB
    __shared__ float4 Hl[128 * 8];   // [row][k4] swizzled 16 KB
    const int t = threadIdx.x;
    const int which = blockIdx.y;
    const float* Wsel = (which == 0) ? WQ : ((which == 1) ? WK : WV);
    const float4* W4 = (const float4*)Wsel;
    const int r0 = blockIdx.x * 128;

    const int tc = t & 15;   // float4 cols tc and tc+16
    const int tr = t >> 4;   // rows tr*8 .. tr*8+7

    float4 acc[8][2];
#pragma unroll
    for (int i = 0; i < 8; ++i) {
        acc[i][0] = make_float4(0.f, 0.f, 0.f, 0.f);
        acc[i][1] = make_float4(0.f, 0.f, 0.f, 0.f);
    }

    for (int kc = 0; kc < 4; ++kc) {
        __syncthreads();   // protect previous chunk's reads
#pragma unroll
        for (int i = 0; i < 4; ++i) {           // Wl: 32 k-rows x 32 float4
            const int idx = t + i * 256;
            const int k = idx >> 5, c = idx & 31;
            Wl[idx] = W4[(size_t)(kc * 32 + k) * 32 + c];
        }
#pragma unroll
        for (int i = 0; i < 4; ++i) {           // Hl: 128 rows x 8 float4
            const int idx = t + i * 256;
            const int row = idx >> 3, kk = idx & 7;
            float4 v = make_float4(0.f, 0.f, 0.f, 0.f);
            if (r0 + row < N)
                v = ((const float4*)h)[(size_t)(r0 + row) * 32 + kc * 8 + kk];
            Hl[row * 8 + (kk ^ ((row >> 3) & 7))] = v;   // swizzled store
        }
        __syncthreads();

        for (int k4 = 0; k4 < 8; ++k4) {
            const float4 b0a = Wl[(k4 * 4 + 0) * 32 + tc];
            const float4 b0b = Wl[(k4 * 4 + 0) * 32 + tc + 16];
            const float4 b1a = Wl[(k4 * 4 + 1) * 32 + tc];
            const float4 b1b = Wl[(k4 * 4 + 1) * 32 + tc + 16];
            const float4 b2a = Wl[(k4 * 4 + 2) * 32 + tc];
            const float4 b2b = Wl[(k4 * 4 + 2) * 32 + tc + 16];
            const float4 b3a = Wl[(k4 * 4 + 3) * 32 + tc];
            const float4 b3b = Wl[(k4 * 4 + 3) * 32 + tc + 16];
#pragma unroll
            for (int r = 0; r < 8; ++r) {
                const int row = tr * 8 + r;
                const float4 a = Hl[row * 8 + (k4 ^ (tr & 7))];  // swizzled read
                FMA4(acc[r][0], a.x, b0a); FMA4(acc[r][1], a.x, b0b);
                FMA4(acc[r][0], a.y, b1a); FMA4(acc[r][1], a.y, b1b);
                FMA4(acc[r][0], a.z, b2a); FMA4(acc[r][1], a.z, b2b);
                FMA4(acc[r][0], a.w, b3a); FMA4(acc[r][1], a.w, b3b);
            }
        }
    }

    if (which == 0) {
        float4* O = (float4*)Qf;
#pragma unroll
        for (int r = 0; r < 8; ++r) {
            const int row = r0 + tr * 8 + r;
            if (row < N) {
                O[(size_t)row * 32 + tc]      = acc[r][0];
                O[(size_t)row * 32 + tc + 16] = acc[r][1];
            }
        }
    } else {
        // acc[r][0] = channels 4tc..4tc+3 = pairs (2tc, 2tc+1): slice s0 =
        // tc>>2, slots j0=(2tc)&7, j0+1. acc[r][1] = pairs (+32): slice s0+4,
        // same slots. K -> float2 lo half (voff 0), V -> hi half (voff 1).
        float2* O2 = (float2*)KVs;
        const int voff = (which == 2) ? 1 : 0;
        const int s0 = tc >> 2;
        const int j0 = (2 * tc) & 7;
#pragma unroll
        for (int r = 0; r < 8; ++r) {
            const int row = r0 + tr * 8 + r;
            if (row < N) {
                const size_t b0 = ((size_t)s0 * N + row) * 8;
                const size_t b1 = ((size_t)(s0 + 4) * N + row) * 8;
                O2[(b0 + j0)     * 2 + voff] = make_float2(acc[r][0].x, acc[r][0].y);
                O2[(b0 + j0 + 1) * 2 + voff] = make_float2(acc[r][0].z, acc[r][0].w);
                O2[(b1 + j0)     * 2 + voff] = make_float2(acc[r][1].x, acc[r][1].y);
                O2[(b1 + j0 + 1) * 2 + voff] = make_float2(acc[r][1].z, acc[r][1].w);
            }
        }
    }
}

// -------------------------- CSR build (stable by dst) ----------------------
__global__ __launch_bounds__(256) void count_deg(
    const int* __restrict__ dst, int* __restrict__ deg, int E)
{
    const int e = blockIdx.x * 256 + threadIdx.x;
    if (e < E) atomicAdd(&deg[dst[e]], 1);
}

__global__ __launch_bounds__(256) void chunk_reduce(
    const int* __restrict__ deg, int* __restrict__ csum, int N)
{
    const int t = threadIdx.x;
    const int i = blockIdx.x * 256 + t;
    int x = (i < N) ? deg[i] : 0;
#pragma unroll
    for (int off = 32; off; off >>= 1) x += __shfl_down(x, off, 64);
    __shared__ int ws[4];
    if ((t & 63) == 0) ws[t >> 6] = x;
    __syncthreads();
    if (t == 0) csum[blockIdx.x] = ws[0] + ws[1] + ws[2] + ws[3];
}

__global__ __launch_bounds__(256) void scan_chunks(
    const int* __restrict__ csum, int* __restrict__ coff, int nChunks)
{
    __shared__ int s[256];
    __shared__ int carry;
    const int t = threadIdx.x;
    if (t == 0) carry = 0;
    __syncthreads();
    for (int base = 0; base < nChunks; base += 256) {
        const int i = base + t;
        int x = (i < nChunks) ? csum[i] : 0;
        s[t] = x;
        __syncthreads();
        for (int off = 1; off < 256; off <<= 1) {
            int v = (t >= off) ? s[t - off] : 0;
            __syncthreads();
            s[t] += v;
            __syncthreads();
        }
        if (i < nChunks) coff[i] = carry + s[t] - x;  // exclusive
        __syncthreads();
        if (t == 0) carry += s[255];
        __syncthreads();
    }
}

__global__ __launch_bounds__(256) void chunk_scan(
    const int* __restrict__ deg, const int* __restrict__ coff,
    int* __restrict__ rowptr, int N)
{
    __shared__ int s[256];
    const int t = threadIdx.x;
    const int i = blockIdx.x * 256 + t;
    int x = (i < N) ? deg[i] : 0;
    s[t] = x;
    __syncthreads();
    for (int off = 1; off < 256; off <<= 1) {
        int v = (t >= off) ? s[t - off] : 0;
        __syncthreads();
        s[t] += v;
        __syncthreads();
    }
    if (i < N) rowptr[i + 1] = coff[blockIdx.x] + s[t];
    if (i == 0) rowptr[0] = 0;
}

// Scatter eids via atomic ticket (arrival order; rank fixes it).
__global__ __launch_bounds__(256) void scatter_eids(
    const int* __restrict__ dst, const int* __restrict__ rowptr,
    int* __restrict__ cur, int* __restrict__ eids, int E)
{
    const int e = blockIdx.x * 256 + threadIdx.x;
    if (e >= E) return;
    const int d = dst[e];
    const int pos = rowptr[d] + atomicAdd(&cur[d], 1);
    eids[pos] = e;
}

// Wave-parallel stable ordering: srcs[lo+rank] = src[eid], ascending eid.
__global__ __launch_bounds__(256) void rank_emit(
    const int* __restrict__ rowptr, const int* __restrict__ eids,
    const int* __restrict__ src, int* __restrict__ srcs, int N)
{
    const int wave = threadIdx.x >> 6;
    const int lane = threadIdx.x & 63;
    const int d = blockIdx.x * 4 + wave;
    if (d >= N) return;
    const int lo = rowptr[d];
    const int deg = rowptr[d + 1] - lo;
    if (deg <= 64) {
        int p = 0x7fffffff;
        if (lane < deg) p = eids[lo + lane];
        int rank = 0;
        for (int j = 0; j < deg; ++j) {
            const int kj = __shfl(p, j, 64);
            rank += (kj < p) ? 1 : 0;
        }
        if (lane < deg) srcs[lo + rank] = src[p];
    } else if (lane == 0) {
        for (int i = 0; i < deg; ++i) {
            const int pi = eids[lo + i];
            int rank = 0;
            for (int j = 0; j < deg; ++j) rank += (eids[lo + j] < pi) ? 1 : 0;
            srcs[lo + rank] = src[pi];
        }
    }
}

// ----------------- degree-sorted dst permutation (counting sort) -----------
__global__ __launch_bounds__(256) void hist_deg(
    const int* __restrict__ deg, int* __restrict__ hist, int N)
{
    const int n = blockIdx.x * 256 + threadIdx.x;
    if (n < N) atomicAdd(&hist[min(deg[n], 127)], 1);
}

__global__ __launch_bounds__(128) void scan_hist(
    const int* __restrict__ hist, int* __restrict__ binoff)
{
    __shared__ int s[128];
    const int t = threadIdx.x;
    const int x = hist[t];
    s[t] = x;
    __syncthreads();
    for (int off = 1; off < 128; off <<= 1) {
        int v = (t >= off) ? s[t - off] : 0;
        __syncthreads();
        s[t] += v;
        __syncthreads();
    }
    binoff[t] = s[t] - x;  // exclusive
}

__global__ __launch_bounds__(256) void scatter_perm(
    const int* __restrict__ deg, const int* __restrict__ binoff,
    int* __restrict__ bincur, int* __restrict__ perm, int N)
{
    const int n = blockIdx.x * 256 + threadIdx.x;
    if (n >= N) return;
    const int b = min(deg[n], 127);
    const int pos = binoff[b] + atomicAdd(&bincur[b], 1);
    perm[pos] = n;
}

// ------------------- np.add.at-order fp32 edge accumulation ----------------
// FROZEN per channel: sc = (k*q)*0.25f; z += sc; wv += v*sc, edges ascending.
// Sliced: gid = dblock*8 + slice (slice -> XCD via round-robin dispatch).
// Block 256 thr = 4 waves; wave = 8 dsts x 8 lanes; lane owns channel pair
// p = slice*8 + j of dst perm[dblock*32 + wave*8 + g]. One dwordx4 per edge.
__global__ __launch_bounds__(256) void attn_out(
    const int* __restrict__ srcs, const int* __restrict__ rowptr,
    const int* __restrict__ perm,
    const float* __restrict__ KVs, const float* __restrict__ Qf,
    float* __restrict__ out, int N)
{
#pragma clang fp contract(off)
    const int gid = blockIdx.x;
    const int slice = gid & 7;
    const int dblock = gid >> 3;
    const int t = threadIdx.x;
    const int wave = t >> 6;
    const int lane = t & 63;
    const int g = lane >> 3, j = lane & 7;
    const int dstIdx = dblock * 32 + wave * 8 + g;
    if (dstIdx >= N) return;
    const int d = perm[dstIdx];
    const float2 q = ((const float2*)Qf)[(size_t)d * 64 + slice * 8 + j];
    const int lo = rowptr[d], hi = rowptr[d + 1];
    const float4* KV4 = (const float4*)KVs;
    const size_t sbase = (size_t)slice * N * 8 + j;
    float2 z = make_float2(0.f, 0.f), wv = z;

#define EDGE_UPD(kv) do { \
        float sc0 = ((kv).x * q.x) * 0.25f; z.x = z.x + sc0; wv.x = wv.x + (kv).z * sc0; \
        float sc1 = ((kv).y * q.y) * 0.25f; z.y = z.y + sc1; wv.y = wv.y + (kv).w * sc1; \
    } while (0)

    int i = lo;
    for (; i + 4 <= hi; i += 4) {
        const int s0 = srcs[i + 0], s1 = srcs[i + 1];
        const int s2 = srcs[i + 2], s3 = srcs[i + 3];
        const float4 kv0 = KV4[sbase + (size_t)s0 * 8];
        const float4 kv1 = KV4[sbase + (size_t)s1 * 8];
        const float4 kv2 = KV4[sbase + (size_t)s2 * 8];
        const float4 kv3 = KV4[sbase + (size_t)s3 * 8];
        EDGE_UPD(kv0); EDGE_UPD(kv1); EDGE_UPD(kv2); EDGE_UPD(kv3);
    }
    for (; i < hi; ++i) {
        const float4 kv = KV4[sbase + (size_t)srcs[i] * 8];
        EDGE_UPD(kv);
    }
#undef EDGE_UPD

    float2 o;
    o.x = wv.x / (z.x + 1e-6f);
    o.y = wv.y / (z.y + 1e-6f);
    ((float2*)out)[(size_t)d * 64 + slice * 8 + j] = o;
}

extern "C" void kernel_launch(void* const* d_in, const int* in_sizes, int n_in,
                              void* d_out, int out_size, void* d_ws, size_t ws_size,
                              hipStream_t stream)
{
    const float* h  = (const float*)d_in[0];
    const int* src  = (const int*)d_in[1];
    const int* dst  = (const int*)d_in[2];
    const float* WQ = (const float*)d_in[3];
    const float* WK = (const float*)d_in[4];
    const float* WV = (const float*)d_in[5];
    const int N = in_sizes[0] / 128;   // 40000
    const int E = in_sizes[1];         // 640000
    const size_t NC = (size_t)N * 128;
    const int nChunks = (N + 255) / 256;

    // Workspace (~70 MB).
    float* KVs = (float*)d_ws;          // N*256 f32, slice-major
    float* Qf  = KVs + (size_t)N * 256; // N*128 f32
    int* deg    = (int*)(Qf + NC);      // N
    int* cur    = deg + N;              // N
    int* hist   = cur + N;              // 128
    int* bincur = hist + 128;           // 128
    int* binoff = bincur + 128;         // 128
    int* perm   = binoff + 128;         // N
    int* rowptr = perm + N;             // N+1
    int* csum   = rowptr + (N + 1);     // nChunks
    int* coff   = csum + nChunks;       // nChunks
    int* srcs   = coff + nChunks;       // E
    int* eids   = srcs + E;             // E
    float* outp = (float*)d_out;

    // zero deg, cur, hist, bincur (contiguous)
    hipMemsetAsync(deg, 0, ((size_t)2 * N + 256) * sizeof(int), stream);

    dim3 ggrid((N + 127) / 128, 3);
    gemm_qkv<<<ggrid, 256, 0, stream>>>(h, WQ, WK, WV, Qf, KVs, N);

    const int eb = (E + 255) / 256;
    const int nb = (N + 255) / 256;
    count_deg<<<eb, 256, 0, stream>>>(dst, deg, E);
    chunk_reduce<<<nChunks, 256, 0, stream>>>(deg, csum, N);
    scan_chunks<<<1, 256, 0, stream>>>(csum, coff, nChunks);
    chunk_scan<<<nChunks, 256, 0, stream>>>(deg, coff, rowptr, N);
    scatter_eids<<<eb, 256, 0, stream>>>(dst, rowptr, cur, eids, E);
    rank_emit<<<(N + 3) / 4, 256, 0, stream>>>(rowptr, eids, src, srcs, N);
    hist_deg<<<nb, 256, 0, stream>>>(deg, hist, N);
    scan_hist<<<1, 128, 0, stream>>>(hist, binoff);
    scatter_perm<<<nb, 256, 0, stream>>>(deg, binoff, bincur, perm, N);

    const int ndblocks = (N + 31) / 32;
    attn_out<<<ndblocks * 8, 256, 0, stream>>>(srcs, rowptr, perm, KVs, Qf, outp, N);
}